// Round 1
// baseline (918.030 us; speedup 1.0000x reference)
//
#include <hip/hip_runtime.h>

#define E_DIM  256
#define N_E    16384
#define N_ROWS 8192
#define HW     1024
#define SPLIT  16
#define BM     128
#define BK     128
#define BD     16

// ---------- prep: transpose embedding [N_E][E_DIM] -> ET [E_DIM][N_E] ----------
__global__ __launch_bounds__(256) void k_transpose(const float* __restrict__ E,
                                                   float* __restrict__ ET) {
  __shared__ float tile[32][33];
  int k0 = blockIdx.x * 32, c0 = blockIdx.y * 32;
  int tx = threadIdx.x & 31, ty = threadIdx.x >> 5;
#pragma unroll
  for (int j = 0; j < 32; j += 8)
    tile[ty + j][tx] = E[(size_t)(k0 + ty + j) * E_DIM + c0 + tx];
  __syncthreads();
#pragma unroll
  for (int j = 0; j < 32; j += 8)
    ET[(size_t)(c0 + ty + j) * N_E + k0 + tx] = tile[tx][ty + j];
}

// ---------- prep: ||e_k||^2 in numpy pairwise order (256 = 128+128, 8 accs) ----------
__global__ __launch_bounds__(256) void k_enorm(const float* __restrict__ E,
                                               float* __restrict__ eNorm) {
#pragma clang fp contract(off)
  int k = blockIdx.x * 256 + threadIdx.x;
  const float* a = E + (size_t)k * E_DIM;
  float halves[2];
  for (int h = 0; h < 2; ++h) {
    const float* p = a + h * 128;
    float r[8];
#pragma unroll
    for (int j = 0; j < 8; ++j) { float v = p[j]; r[j] = v * v; }
    for (int i = 8; i < 128; i += 8) {
#pragma unroll
      for (int j = 0; j < 8; ++j) { float v = p[i + j]; r[j] = r[j] + v * v; }
    }
    halves[h] = ((r[0] + r[1]) + (r[2] + r[3])) + ((r[4] + r[5]) + (r[6] + r[7]));
  }
  eNorm[k] = halves[0] + halves[1];
}

// ---------- prep: ||z_n||^2, same numpy pairwise order (stride HW over channels) ----------
__global__ __launch_bounds__(256) void k_znorm(const float* __restrict__ z,
                                               float* __restrict__ zNorm) {
#pragma clang fp contract(off)
  int n = blockIdx.x * 256 + threadIdx.x;
  int b = n >> 10, hw = n & 1023;
  const float* p = z + (size_t)b * E_DIM * HW + hw;
  float halves[2];
  for (int h = 0; h < 2; ++h) {
    const float* a = p + (size_t)h * 128 * HW;
    float r[8];
#pragma unroll
    for (int j = 0; j < 8; ++j) { float v = a[(size_t)j * HW]; r[j] = v * v; }
    for (int i = 8; i < 128; i += 8) {
#pragma unroll
      for (int j = 0; j < 8; ++j) { float v = a[(size_t)(i + j) * HW]; r[j] = r[j] + v * v; }
    }
    halves[h] = ((r[0] + r[1]) + (r[2] + r[3])) + ((r[4] + r[5]) + (r[6] + r[7]));
  }
  zNorm[n] = halves[0] + halves[1];
}

// ---------- main: fp32 GEMM + running quantized-score argmin ----------
// grid (N_ROWS/BM, SPLIT); block 256 = 16x16 threads, 8x8 tile each (split 4+4)
__global__ __launch_bounds__(256) void k_scores(
    const float* __restrict__ z, const float* __restrict__ ET,
    const float* __restrict__ eNorm, const float* __restrict__ zNorm,
    float* __restrict__ pVal, int* __restrict__ pIdx) {
#pragma clang fp contract(off)
  __shared__ float Zs[BD][BM];
  __shared__ float Es[BD][BK];

  const int mt = blockIdx.x, ks = blockIdx.y;
  const int n0 = mt * BM;
  const int b = n0 >> 10;
  const int hw0 = n0 & 1023;
  const float* zbase = z + (size_t)b * E_DIM * HW + hw0;

  const int t = threadIdx.x;
  const int tx = t & 15, ty = t >> 4;
  const int r0 = ty * 4, c0l = tx * 4;

  float minv[8], zn[8];
  int mini[8];
#pragma unroll
  for (int i = 0; i < 8; ++i) { minv[i] = 3.4e38f; mini[i] = 0; }
#pragma unroll
  for (int i = 0; i < 8; ++i) {
    int roff = r0 + ((i < 4) ? i : 60 + i);
    zn[i] = zNorm[n0 + roff];
  }

  const int ld_dd = t >> 5;         // 0..7
  const int ld_p = (t & 31) * 4;    // 0..124

  for (int kc = 0; kc < (N_E / SPLIT) / BK; ++kc) {
    const int k0 = ks * (N_E / SPLIT) + kc * BK;
    float acc[8][8];
#pragma unroll
    for (int i = 0; i < 8; ++i)
#pragma unroll
      for (int j = 0; j < 8; ++j) acc[i][j] = 0.f;

    for (int dc = 0; dc < E_DIM / BD; ++dc) {
      const int d0 = dc * BD;
#pragma unroll
      for (int h = 0; h < 2; ++h) {
        int dd = ld_dd + h * 8;
        *(float4*)&Zs[dd][ld_p] = *(const float4*)&zbase[(size_t)(d0 + dd) * HW + ld_p];
        *(float4*)&Es[dd][ld_p] = *(const float4*)&ET[(size_t)(d0 + dd) * N_E + k0 + ld_p];
      }
      __syncthreads();
#pragma unroll
      for (int dd = 0; dd < BD; ++dd) {
        const float4 a0 = *(const float4*)&Zs[dd][r0];
        const float4 a1 = *(const float4*)&Zs[dd][r0 + 64];
        const float4 b0 = *(const float4*)&Es[dd][c0l];
        const float4 b1 = *(const float4*)&Es[dd][c0l + 64];
        const float av[8] = {a0.x, a0.y, a0.z, a0.w, a1.x, a1.y, a1.z, a1.w};
        const float bv[8] = {b0.x, b0.y, b0.z, b0.w, b1.x, b1.y, b1.z, b1.w};
#pragma unroll
        for (int i = 0; i < 8; ++i)
#pragma unroll
          for (int j = 0; j < 8; ++j)
            acc[i][j] = fmaf(av[i], bv[j], acc[i][j]);
      }
      __syncthreads();
    }
    // quantized score exactly like reference: fl(fl(zn+en) - fl(2*dot))
#pragma unroll
    for (int j = 0; j < 8; ++j) {
      const int cc = k0 + c0l + ((j < 4) ? j : 60 + j);
      const float en = eNorm[cc];
#pragma unroll
      for (int i = 0; i < 8; ++i) {
        float tsum = zn[i] + en;
        float s = tsum - 2.0f * acc[i][j];
        if (s < minv[i]) { minv[i] = s; mini[i] = cc; }   // strict <: first-occurrence ties
      }
    }
  }
  // reduce (val, idx) lexicographically across the 16 tx lanes of each wave
#pragma unroll
  for (int off = 1; off < 16; off <<= 1) {
#pragma unroll
    for (int i = 0; i < 8; ++i) {
      float ov = __shfl_xor(minv[i], off, 64);
      int oi = __shfl_xor(mini[i], off, 64);
      if (ov < minv[i] || (ov == minv[i] && oi < mini[i])) { minv[i] = ov; mini[i] = oi; }
    }
  }
  if (tx == 0) {
#pragma unroll
    for (int i = 0; i < 8; ++i) {
      int r = n0 + r0 + ((i < 4) ? i : 60 + i);
      pVal[(size_t)r * SPLIT + ks] = minv[i];
      pIdx[(size_t)r * SPLIT + ks] = mini[i];
    }
  }
}

// ---------- finalize argmin across SPLIT partials; write idx (as float); zero loss ----------
__global__ __launch_bounds__(256) void k_finalize(const float* __restrict__ pVal,
                                                  const int* __restrict__ pIdx,
                                                  int* __restrict__ fIdx,
                                                  float* __restrict__ out_idx,
                                                  float* __restrict__ out_loss) {
  int n = blockIdx.x * 256 + threadIdx.x;
  float mv = 3.4e38f;
  int mi = 0;
#pragma unroll
  for (int s2 = 0; s2 < SPLIT; ++s2) {
    float v = pVal[(size_t)n * SPLIT + s2];
    int id = pIdx[(size_t)n * SPLIT + s2];
    if (v < mv || (v == mv && id < mi)) { mv = v; mi = id; }
  }
  fIdx[n] = mi;
  out_idx[n] = (float)mi;
  if (n == 0) out_loss[0] = 0.f;
}

// ---------- gather z_q to (b,c,h,w) + fused loss = 1.25*mean((zq-z)^2) ----------
__global__ __launch_bounds__(256) void k_gather_loss(
    const float* __restrict__ z, const float* __restrict__ E,
    const int* __restrict__ fIdx, float* __restrict__ out,
    float* __restrict__ out_loss) {
  int n = blockIdx.x * 256 + threadIdx.x;
  int b = n >> 10, hw = n & 1023;
  int idx = fIdx[n];
  const float* erow = E + (size_t)idx * E_DIM;
  const float* zrow = z + (size_t)b * E_DIM * HW + hw;
  float* orow = out + (size_t)b * E_DIM * HW + hw;
  float s = 0.f;
#pragma unroll 4
  for (int c = 0; c < E_DIM; ++c) {
    float e = erow[c];
    float zv = zrow[(size_t)c * HW];
    orow[(size_t)c * HW] = e;
    float d = e - zv;
    s = fmaf(d, d, s);
  }
  for (int off = 32; off > 0; off >>= 1) s += __shfl_down(s, off, 64);
  __shared__ float wsum[4];
  if ((threadIdx.x & 63) == 0) wsum[threadIdx.x >> 6] = s;
  __syncthreads();
  if (threadIdx.x == 0) {
    float tot = (wsum[0] + wsum[1]) + (wsum[2] + wsum[3]);
    atomicAdd(out_loss, tot * (1.25f / 2097152.f));
  }
}

extern "C" void kernel_launch(void* const* d_in, const int* in_sizes, int n_in,
                              void* d_out, int out_size, void* d_ws, size_t ws_size,
                              hipStream_t stream) {
  const float* z = (const float*)d_in[0];
  const float* E = (const float*)d_in[1];
  float* out = (float*)d_out;
  float* out_loss = out + 2097152;  // after z_q (8*256*32*32)
  float* out_idx = out + 2097153;   // after loss scalar

  // workspace layout (floats): ET | eNorm | zNorm | pVal | pIdx | fIdx  (~18 MB)
  float* ET = (float*)d_ws;
  float* eNorm = ET + (size_t)E_DIM * N_E;
  float* zNorm = eNorm + N_E;
  float* pVal = zNorm + N_ROWS;
  int* pIdx = (int*)(pVal + (size_t)N_ROWS * SPLIT);
  int* fIdx = pIdx + (size_t)N_ROWS * SPLIT;

  k_transpose<<<dim3(N_E / 32, E_DIM / 32), 256, 0, stream>>>(E, ET);
  k_enorm<<<N_E / 256, 256, 0, stream>>>(E, eNorm);
  k_znorm<<<N_ROWS / 256, 256, 0, stream>>>(z, zNorm);
  k_scores<<<dim3(N_ROWS / BM, SPLIT), 256, 0, stream>>>(z, ET, eNorm, zNorm, pVal, pIdx);
  k_finalize<<<N_ROWS / 256, 256, 0, stream>>>(pVal, pIdx, fIdx, out_idx, out_loss);
  k_gather_loss<<<N_ROWS / 256, 256, 0, stream>>>(z, E, fIdx, out, out_loss);
}

// Round 2
// 455.885 us; speedup vs baseline: 2.0137x; 2.0137x over previous
//
#include <hip/hip_runtime.h>

#define E_DIM  256
#define N_E    16384
#define N_ROWS 8192
#define HW     1024
#define NPART  128          // n-tiles of 128 cols -> partial argmins per row

typedef _Float16 f16x8 __attribute__((ext_vector_type(8)));
typedef _Float16 f16x4 __attribute__((ext_vector_type(4)));
typedef float    f32x4 __attribute__((ext_vector_type(4)));

#define ESCALE   1048576.0f          // 2^20 (exact)
#define UNSCALE  1.9073486328125e-6f // 2^-19: acc*2^-19 == 2*dot

// ---------- prep: E -> scaled fp16 limbs (eh, el), coalesced elementwise ----------
__global__ __launch_bounds__(256) void k_e_limbs(const float* __restrict__ E,
                                                 _Float16* __restrict__ eh,
                                                 _Float16* __restrict__ el) {
  size_t i4 = ((size_t)blockIdx.x * 256 + threadIdx.x) * 4;
  float4 v = *(const float4*)&E[i4];
  float s[4] = {v.x * ESCALE, v.y * ESCALE, v.z * ESCALE, v.w * ESCALE};
  f16x4 h, l;
#pragma unroll
  for (int j = 0; j < 4; ++j) {
    _Float16 hh = (_Float16)s[j];
    h[j] = hh;
    l[j] = (_Float16)(s[j] - (float)hh);
  }
  *(f16x4*)&eh[i4] = h;
  *(f16x4*)&el[i4] = l;
}

// ---------- prep: z [b][c][hw] -> limbs zh,zl in [n][c] layout (tiled transpose) ----------
__global__ __launch_bounds__(256) void k_z_limbs(const float* __restrict__ z,
                                                 _Float16* __restrict__ zh,
                                                 _Float16* __restrict__ zl) {
  __shared__ float tile[32][33];
  int b = blockIdx.z;
  int hw0 = blockIdx.x * 32, c0 = blockIdx.y * 32;
  int tx = threadIdx.x & 31, ty = threadIdx.x >> 5;
#pragma unroll
  for (int j = 0; j < 32; j += 8)
    tile[ty + j][tx] = z[((size_t)b * E_DIM + c0 + ty + j) * HW + hw0 + tx];
  __syncthreads();
#pragma unroll
  for (int j = 0; j < 32; j += 8) {
    float v = tile[tx][ty + j];               // [c_local=tx][hw_local=ty+j]
    _Float16 h = (_Float16)v;
    _Float16 l = (_Float16)(v - (float)h);
    size_t n = (size_t)b * HW + hw0 + ty + j;
    zh[n * E_DIM + c0 + tx] = h;
    zl[n * E_DIM + c0 + tx] = l;
  }
}

// ---------- prep: ||e_k||^2 in numpy pairwise order (256 = 128+128, 8 accs) ----------
__global__ __launch_bounds__(256) void k_enorm(const float* __restrict__ E,
                                               float* __restrict__ eNorm) {
#pragma clang fp contract(off)
  int k = blockIdx.x * 256 + threadIdx.x;
  const float* a = E + (size_t)k * E_DIM;
  float halves[2];
  for (int h = 0; h < 2; ++h) {
    const float* p = a + h * 128;
    float r[8];
#pragma unroll
    for (int j = 0; j < 8; ++j) { float v = p[j]; r[j] = v * v; }
    for (int i = 8; i < 128; i += 8) {
#pragma unroll
      for (int j = 0; j < 8; ++j) { float v = p[i + j]; r[j] = r[j] + v * v; }
    }
    halves[h] = ((r[0] + r[1]) + (r[2] + r[3])) + ((r[4] + r[5]) + (r[6] + r[7]));
  }
  eNorm[k] = halves[0] + halves[1];
}

// ---------- prep: ||z_n||^2, same numpy pairwise order ----------
__global__ __launch_bounds__(256) void k_znorm(const float* __restrict__ z,
                                               float* __restrict__ zNorm) {
#pragma clang fp contract(off)
  int n = blockIdx.x * 256 + threadIdx.x;
  int b = n >> 10, hw = n & 1023;
  const float* p = z + (size_t)b * E_DIM * HW + hw;
  float halves[2];
  for (int h = 0; h < 2; ++h) {
    const float* a = p + (size_t)h * 128 * HW;
    float r[8];
#pragma unroll
    for (int j = 0; j < 8; ++j) { float v = a[(size_t)j * HW]; r[j] = v * v; }
    for (int i = 8; i < 128; i += 8) {
#pragma unroll
      for (int j = 0; j < 8; ++j) { float v = a[(size_t)(i + j) * HW]; r[j] = r[j] + v * v; }
    }
    halves[h] = ((r[0] + r[1]) + (r[2] + r[3])) + ((r[4] + r[5]) + (r[6] + r[7]));
  }
  zNorm[n] = halves[0] + halves[1];
}

// ---------- main: 3-pass fp16-limb MFMA GEMM + per-128-col argmin ----------
// grid (64 m-tiles, 128 n-tiles), 256 threads = 4 waves, each wave 64x64
__global__ __launch_bounds__(256) void k_scores_mfma(
    const _Float16* __restrict__ zh, const _Float16* __restrict__ zl,
    const _Float16* __restrict__ eh, const _Float16* __restrict__ el,
    const float* __restrict__ eNorm, const float* __restrict__ zNorm,
    float* __restrict__ pVal, int* __restrict__ pIdx) {
#pragma clang fp contract(off)
  __shared__ _Float16 As[2][128][40];   // limb, row, k (pad 32->40: 16B-aligned rows)
  __shared__ _Float16 Bs[2][128][40];

  const int mt = blockIdx.x, nt = blockIdx.y;
  const int m0 = mt * 128, n0 = nt * 128;

  const int t = threadIdx.x;
  const int lane = t & 63, w = t >> 6;
  const int tx = lane & 15, quad = lane >> 4;
  const int wm = (w >> 1) * 64, wn = (w & 1) * 64;

  const int srow = t >> 2;          // 0..63
  const int skp = (t & 3) * 8;      // f16 offset 0,8,16,24

  f32x4 acc[4][4];
#pragma unroll
  for (int i = 0; i < 4; ++i)
#pragma unroll
    for (int j = 0; j < 4; ++j) acc[i][j] = (f32x4){0.f, 0.f, 0.f, 0.f};

  for (int kc = 0; kc < 8; ++kc) {
    const int k0 = kc * 32;
    __syncthreads();
    {
      const size_t a0 = (size_t)(m0 + srow) * E_DIM + k0 + skp;
      const size_t a1 = a0 + (size_t)64 * E_DIM;
      *(float4*)&As[0][srow][skp]      = *(const float4*)&zh[a0];
      *(float4*)&As[0][srow + 64][skp] = *(const float4*)&zh[a1];
      *(float4*)&As[1][srow][skp]      = *(const float4*)&zl[a0];
      *(float4*)&As[1][srow + 64][skp] = *(const float4*)&zl[a1];
      const size_t b0 = (size_t)(n0 + srow) * E_DIM + k0 + skp;
      const size_t b1 = b0 + (size_t)64 * E_DIM;
      *(float4*)&Bs[0][srow][skp]      = *(const float4*)&eh[b0];
      *(float4*)&Bs[0][srow + 64][skp] = *(const float4*)&eh[b1];
      *(float4*)&Bs[1][srow][skp]      = *(const float4*)&el[b0];
      *(float4*)&Bs[1][srow + 64][skp] = *(const float4*)&el[b1];
    }
    __syncthreads();

    f16x8 ah[4], alo[4], bh[4], blo[4];
#pragma unroll
    for (int i = 0; i < 4; ++i) {
      ah[i]  = *(const f16x8*)&As[0][wm + i * 16 + tx][quad * 8];
      alo[i] = *(const f16x8*)&As[1][wm + i * 16 + tx][quad * 8];
      bh[i]  = *(const f16x8*)&Bs[0][wn + i * 16 + tx][quad * 8];
      blo[i] = *(const f16x8*)&Bs[1][wn + i * 16 + tx][quad * 8];
    }
#pragma unroll
    for (int i = 0; i < 4; ++i)
#pragma unroll
      for (int j = 0; j < 4; ++j) {
        acc[i][j] = __builtin_amdgcn_mfma_f32_16x16x32_f16(ah[i],  bh[j],  acc[i][j], 0, 0, 0);
        acc[i][j] = __builtin_amdgcn_mfma_f32_16x16x32_f16(ah[i],  blo[j], acc[i][j], 0, 0, 0);
        acc[i][j] = __builtin_amdgcn_mfma_f32_16x16x32_f16(alo[i], bh[j],  acc[i][j], 0, 0, 0);
      }
  }

  // ---- epilogue: score + argmin (first-index tie-break) ----
  __syncthreads();
  float* sF  = (float*)&As[0][0][0];
  float* zNl = sF;            // [128]
  float* eNl = sF + 128;      // [128]
  float* sV  = sF + 256;      // [2][128]
  int*   sI  = (int*)(sF + 512);  // [2][128]
  if (t < 128) zNl[t] = zNorm[m0 + t];
  else         eNl[t - 128] = eNorm[n0 + t - 128];
  __syncthreads();

#pragma unroll
  for (int i = 0; i < 4; ++i) {
#pragma unroll
    for (int r = 0; r < 4; ++r) {
      const int rloc = wm + i * 16 + quad * 4 + r;
      const float zn = zNl[rloc];
      float bv = 3.4e38f;
      int bc = 0x7fffffff;
#pragma unroll
      for (int j = 0; j < 4; ++j) {
        float en = eNl[wn + j * 16 + tx];
        float s = (zn + en) - acc[i][j][r] * UNSCALE;
        int c = n0 + wn + j * 16 + tx;
        if (s < bv) { bv = s; bc = c; }   // cols ascending in j: strict < keeps lowest
      }
#pragma unroll
      for (int off = 1; off < 16; off <<= 1) {
        float ov = __shfl_xor(bv, off, 64);
        int oc = __shfl_xor(bc, off, 64);
        if (ov < bv || (ov == bv && oc < bc)) { bv = ov; bc = oc; }
      }
      if (tx == 0) { sV[(w & 1) * 128 + rloc] = bv; sI[(w & 1) * 128 + rloc] = bc; }
    }
  }
  __syncthreads();
  if (t < 128) {
    float v0 = sV[t], v1 = sV[128 + t];
    int i0 = sI[t], i1 = sI[128 + t];
    int take1 = (v1 < v0);                 // tie -> half 0 (smaller idx)
    pVal[(size_t)(m0 + t) * NPART + nt] = take1 ? v1 : v0;
    pIdx[(size_t)(m0 + t) * NPART + nt] = take1 ? i1 : i0;
  }
}

// ---------- finalize argmin across NPART partials; write idx (as float); zero loss ----------
__global__ __launch_bounds__(256) void k_finalize(const float* __restrict__ pVal,
                                                  const int* __restrict__ pIdx,
                                                  int* __restrict__ fIdx,
                                                  float* __restrict__ out_idx,
                                                  float* __restrict__ out_loss) {
  int n = blockIdx.x * 256 + threadIdx.x;
  float mv = 3.4e38f;
  int mi = 0x7fffffff;
  for (int s2 = 0; s2 < NPART; ++s2) {
    float v = pVal[(size_t)n * NPART + s2];
    int id = pIdx[(size_t)n * NPART + s2];
    if (v < mv || (v == mv && id < mi)) { mv = v; mi = id; }
  }
  fIdx[n] = mi;
  out_idx[n] = (float)mi;
  if (n == 0) out_loss[0] = 0.f;
}

// ---------- gather z_q to (b,c,h,w) + fused loss = 1.25*mean((zq-z)^2) ----------
__global__ __launch_bounds__(256) void k_gather_loss(
    const float* __restrict__ z, const float* __restrict__ E,
    const int* __restrict__ fIdx, float* __restrict__ out,
    float* __restrict__ out_loss) {
  int n = blockIdx.x * 256 + threadIdx.x;
  int b = n >> 10, hw = n & 1023;
  int idx = fIdx[n];
  const float* erow = E + (size_t)idx * E_DIM;
  const float* zrow = z + (size_t)b * E_DIM * HW + hw;
  float* orow = out + (size_t)b * E_DIM * HW + hw;
  float s = 0.f;
#pragma unroll 4
  for (int c = 0; c < E_DIM; ++c) {
    float e = erow[c];
    float zv = zrow[(size_t)c * HW];
    orow[(size_t)c * HW] = e;
    float d = e - zv;
    s = fmaf(d, d, s);
  }
  for (int off = 32; off > 0; off >>= 1) s += __shfl_down(s, off, 64);
  __shared__ float wsum[4];
  if ((threadIdx.x & 63) == 0) wsum[threadIdx.x >> 6] = s;
  __syncthreads();
  if (threadIdx.x == 0) {
    float tot = (wsum[0] + wsum[1]) + (wsum[2] + wsum[3]);
    atomicAdd(out_loss, tot * (1.25f / 2097152.f));
  }
}

extern "C" void kernel_launch(void* const* d_in, const int* in_sizes, int n_in,
                              void* d_out, int out_size, void* d_ws, size_t ws_size,
                              hipStream_t stream) {
  const float* z = (const float*)d_in[0];
  const float* E = (const float*)d_in[1];
  float* out = (float*)d_out;
  float* out_loss = out + 2097152;  // after z_q (8*256*32*32)
  float* out_idx = out + 2097153;   // after loss scalar

  // workspace layout (~34 MB): zh|zl (f16 [8192][256]) eh|el (f16 [16384][256])
  //                            eNorm zNorm pVal pIdx fIdx
  _Float16* zh = (_Float16*)d_ws;
  _Float16* zl = zh + (size_t)N_ROWS * E_DIM;
  _Float16* eh = zl + (size_t)N_ROWS * E_DIM;
  _Float16* el = eh + (size_t)N_E * E_DIM;
  float* eNorm = (float*)(el + (size_t)N_E * E_DIM);
  float* zNorm = eNorm + N_E;
  float* pVal = zNorm + N_ROWS;
  int* pIdx = (int*)(pVal + (size_t)N_ROWS * NPART);
  int* fIdx = pIdx + (size_t)N_ROWS * NPART;

  k_e_limbs<<<(N_E * E_DIM) / 1024, 256, 0, stream>>>(E, eh, el);
  k_z_limbs<<<dim3(HW / 32, E_DIM / 32, 8), 256, 0, stream>>>(z, zh, zl);
  k_enorm<<<N_E / 256, 256, 0, stream>>>(E, eNorm);
  k_znorm<<<N_ROWS / 256, 256, 0, stream>>>(z, zNorm);
  k_scores_mfma<<<dim3(N_ROWS / 128, N_E / 128), 256, 0, stream>>>(
      zh, zl, eh, el, eNorm, zNorm, pVal, pIdx);
  k_finalize<<<N_ROWS / 256, 256, 0, stream>>>(pVal, pIdx, fIdx, out_idx, out_loss);
  k_gather_loss<<<N_ROWS / 256, 256, 0, stream>>>(z, E, fIdx, out, out_loss);
}